// Round 1
// baseline (86.507 us; speedup 1.0000x reference)
//
#include <hip/hip_runtime.h>
#include <math.h>

// Per-row VQ via per-block SORTED codebook + PRECOMPUTED EXACT DECISION
// THRESHOLDS.
//   x: [4096, 2048] fp32, values: [4096, 16] fp32
//   out[r][c] = values[r][argmin_v fl(fl(x-v)^2)], first-index tie-break.
//
// Replaces the per-element {binary search + 2x Entry load + 4 distance ops +
// 6-op tie-break} with a pure rank computation against 15 precomputed
// thresholds T[k] = minimal float x for which the bit-exact comparator
//     takeR = (dR<dL) | (dR==dL & idxR<idxL)
// prefers sorted[k] over sorted[k-1]. The comparator is monotone in x on
// [sorted[k-1], sorted[k]] (dL=fl(fl(x-a)^2) non-decreasing, dR non-
// increasing, tie region is an interval resolved by a constant index test),
// so a 32-step bisection over ordered float bits finds T[k] exactly.
// Strict-vs-inclusive folds into the threshold itself (floats are discrete:
// x > t  <=>  x >= nextafter(t)), so the hot loop needs only (T[k] <= x).
//
// Exactness: inside each sorted interval the decision is bit-identical to
// the previous (absmax 0.0) kernel. Residual divergence exists only for
// degenerate rounding ties (underflowing squares / ties outside [a,b]),
// where the two candidate VALUES differ by < ~1e-6 -- four orders below
// the 8.9e-2 pass threshold.
//
// Issue-count model (measured 0.102 us per VALU issue/element):
//   old: ~14 search + 4 dist + 6 select + LDS = ~25/elem
//   new: ~12 VALU + 3 ds_read_b32             = ~15/elem  -> predict -1..-2.5 us.
// All per-element LDS reads touch <=16 distinct 4B-strided addresses
// (distinct banks) -> conflict-free.

#define N_ROWS 4096
#define N_COLS 2048
#define N_VALS 16

typedef float f32x4 __attribute__((ext_vector_type(4)));

// Monotone float<->ordered-uint mapping (total order matching float <).
__device__ __forceinline__ unsigned ford(unsigned u) {
    return (u & 0x80000000u) ? ~u : (u | 0x80000000u);
}
__device__ __forceinline__ unsigned funord(unsigned o) {
    return (o & 0x80000000u) ? (o & 0x7fffffffu) : ~o;
}

__global__ __launch_bounds__(256) void vq_rowcodebook_kernel(
    const float* __restrict__ x,
    const float* __restrict__ values,
    float* __restrict__ out)
{
    const int row = blockIdx.x;
    const float* vr = values + (size_t)row * N_VALS;
    const int tid = threadIdx.x;

    // LUT[0]     : unused (-inf sentinel, never read by the search)
    // LUT[1..15] : decision thresholds, ascending
    // LUT[16..31]: sorted codebook values, ascending (byte offset 64)
    __shared__ float LUT[32];
    __shared__ int   SIDX[16];   // original index of sorted[k] (setup only)

    // ---- Phase 1: stable sort by rank (16 lanes) --------------------------
    if (tid < N_VALS) {
        const float vi = vr[tid];
        int rank = 0;
#pragma unroll
        for (int j = 0; j < N_VALS; ++j) {
            const float vj = vr[j];
            rank += (vj < vi || (vj == vi && j < tid)) ? 1 : 0;
        }
        LUT[16 + rank] = vi;
        SIDX[rank] = tid;
        if (tid == 0) LUT[0] = -INFINITY;
    }
    __syncthreads();

    // ---- Phase 2: exact threshold per boundary via bit-space bisection ----
    // T[k] = minimal float x (in [a, nextafter(b)]) where the bit-exact
    // comparator prefers b = sorted[k] over a = sorted[k-1]. Virtual
    // "true" at ord(b)+1 handles the never-true (duplicate) case; the
    // resulting off-by-one-ulp decisions only occur between values that
    // are numerically identical to ~1e-6.
    if (tid >= 1 && tid < N_VALS) {
        const float a = LUT[16 + tid - 1];
        const float b = LUT[16 + tid];
        const int  ia = SIDX[tid - 1];
        const int  ib = SIDX[tid];
        unsigned L = ford(__float_as_uint(a));
        unsigned H = ford(__float_as_uint(b)) + 1u;
        while (L < H) {                       // <= 32 iterations, setup-only
            const unsigned M = L + ((H - L) >> 1);   // M <= ord(b): valid float
            const float xm = __uint_as_float(funord(M));
            const float tL = xm - a;
            const float tR = xm - b;
            const float dL = tL * tL;         // same double-rounding as ref
            const float dR = tR * tR;
            const bool takeR = (dR < dL) || ((dR == dL) && (ib < ia));
            if (takeR) H = M; else L = M + 1;
        }
        LUT[tid] = __uint_as_float(funord(L));
    }
    __syncthreads();

    // ---- Phase 3: hot loop — rank(x) over thresholds, then gather ---------
    // Levels 1-2 from registers, levels 3-4 as single-dword LDS reads with
    // immediate offsets, final sorted-value gather at byte offset 64.
    const float t8  = LUT[8];
    const float t4  = LUT[4];
    const float t12 = LUT[12];
    const char* base = (const char*)LUT;

    const f32x4* xr   = (const f32x4*)(x   + (size_t)row * N_COLS);
    f32x4*       outr = (f32x4*)      (out + (size_t)row * N_COLS);

    // 2048 cols = 512 float4; 256 threads -> 2 iterations, fully coalesced.
#pragma unroll
    for (int it = 0; it < 2; ++it) {
        const int j = tid + it * 256;
        const f32x4 xv = xr[j];

        f32x4 o;
#pragma unroll
        for (int e = 0; e < 4; ++e) {
            const float xe = xv[e];

            // Branchless "find last k with T[k] <= x" over T[1..15];
            // posB is the byte offset of index k (4 B/entry).
            const bool b1 = (t8 <= xe);
            int posB = b1 ? 32 : 0;
            const float tq = b1 ? t12 : t4;
            posB += (tq <= xe) ? 16 : 0;
            posB += (*(const float*)(base + posB + 8) <= xe) ? 8 : 0;
            posB += (*(const float*)(base + posB + 4) <= xe) ? 4 : 0;

            o[e] = *(const float*)(base + posB + 64);  // sorted[rank]
        }
        outr[j] = o;
    }
}

extern "C" void kernel_launch(void* const* d_in, const int* in_sizes, int n_in,
                              void* d_out, int out_size, void* d_ws, size_t ws_size,
                              hipStream_t stream) {
    const float* x      = (const float*)d_in[0];
    const float* values = (const float*)d_in[1];
    float* out          = (float*)d_out;

    vq_rowcodebook_kernel<<<N_ROWS, 256, 0, stream>>>(x, values, out);
}

// Round 2
// 85.205 us; speedup vs baseline: 1.0153x; 1.0153x over previous
//
#include <hip/hip_runtime.h>
#include <math.h>

// Per-row VQ: per-block SORTED codebook + PRECOMPUTED EXACT DECISION THRESHOLDS.
//   x: [4096, 2048] fp32, values: [4096, 16] fp32
//   out[r][c] = values[r][argmin_v fl(fl(x-v)^2)], first-index tie-break.
//
// v2 of the threshold kernel. The hot loop (rank over 15 thresholds, then
// gather) is bit-identical to v1 (passed absmax 0.0). v1 regressed because
// its setup -- a 32-iter serial bisection in 1 of 4 waves, behind a
// vmcnt-draining barrier, before any x-load was issued -- serialized ~2000
// cycles of per-block critical path with nothing to hide it.
//
// v2 makes setup free:
//  - ROWS_PER_BLOCK=2: 2048 blocks = exactly one fully-resident round
//    (8 blocks/CU x 256 CU, 32 waves/CU). Bisections for both rows run
//    concurrently in wave 0 (30 active lanes); total setup work halved.
//  - x float4 prefetch issued at the TOP of the kernel: the mandatory HBM
//    stream (per-CU ~10 us) starts at t=0 and hides the ~0.9 us setup chain
//    (values-load -> sort -> bisect) entirely.
//  - bisection starts at ord(a)+1 (takeR provably false at x=a) and hoists
//    the tie-winner bool (loop body ~11 ops).
//
// Exactness: threshold T[k] is the exact transition point of the bit-exact
// comparator (dR<dL) | (dR==dL & idxR<idxL) on [sorted[k-1], sorted[k]]
// (monotone: dL nondecr., dR nonincr., tie region an interval with constant
// index resolution), found by bisection over ordered float bits. Residual
// divergence only in degenerate underflow ties where candidate VALUES differ
// by < 1e-6 -- four orders below the 8.9e-2 threshold.
//
// Hot-loop cost: ~10 VALU + 3 ds_read_b32 per element, all LDS addresses on
// distinct banks (search: dwords {2,6,10,14} / {1,3,..,15}; gather: dwords
// 16..31) -> conflict-free.

#define N_ROWS 4096
#define N_COLS 2048
#define N_VALS 16
#define ROWS_PER_BLOCK 2

typedef float f32x4 __attribute__((ext_vector_type(4)));

// Monotone float<->ordered-uint mapping (total order matching float <).
__device__ __forceinline__ unsigned ford(unsigned u) {
    return (u & 0x80000000u) ? ~u : (u | 0x80000000u);
}
__device__ __forceinline__ unsigned funord(unsigned o) {
    return (o & 0x80000000u) ? (o & 0x7fffffffu) : ~o;
}

__global__ __launch_bounds__(256) void vq_rowcodebook_kernel(
    const float* __restrict__ x,
    const float* __restrict__ values,
    float* __restrict__ out)
{
    const int row0 = blockIdx.x * ROWS_PER_BLOCK;
    const int tid = threadIdx.x;

    // Per row: [0] unused, [1..15] thresholds asc, [16..31] sorted values asc.
    __shared__ float LUT[ROWS_PER_BLOCK][32];
    __shared__ int   SIDX[ROWS_PER_BLOCK][16];   // original index of sorted[k]

    // ---- Prefetch x at t=0: HBM streams under the whole setup phase -------
    const f32x4* xr0 = (const f32x4*)(x + (size_t)row0 * N_COLS);
    f32x4 xv0 = xr0[tid];
    f32x4 xv1 = xr0[256 + tid];
    f32x4 xv2 = xr0[512 + tid];          // row0+1 starts at float4 index 512
    f32x4 xv3 = xr0[768 + tid];

    // ---- Phase 1: stable sort by rank (wave 0, lanes 0..31) ---------------
    if (tid < ROWS_PER_BLOCK * N_VALS) {
        const int rr = tid >> 4, i = tid & 15;
        const float* vr = values + (size_t)(row0 + rr) * N_VALS;
        const float vi = vr[i];
        int rank = 0;
#pragma unroll
        for (int j = 0; j < N_VALS; ++j) {
            const float vj = vr[j];
            rank += (vj < vi || (vj == vi && j < i)) ? 1 : 0;
        }
        LUT[rr][16 + rank] = vi;
        SIDX[rr][rank] = i;
    }
    __syncthreads();

    // ---- Phase 2: exact threshold per boundary (wave 0, 30 lanes) ---------
    // T[k] = minimal float x in (a, nextafter(b)] where the comparator
    // prefers b = sorted[k] over a = sorted[k-1]. takeR is false at x=a
    // (dL=0 < dR; underflow-tie edge resolves to a value < 1e-70 away),
    // so start at ord(a)+1. Virtual "true" at ord(b)+1 handles duplicates.
    if (tid < ROWS_PER_BLOCK * N_VALS) {
        const int rr = tid >> 4, i = tid & 15;
        if (i >= 1) {
            const float a = LUT[rr][16 + i - 1];
            const float b = LUT[rr][16 + i];
            const bool tiewin = (SIDX[rr][i] < SIDX[rr][i - 1]);  // ib < ia
            unsigned L = ford(__float_as_uint(a)) + 1u;
            unsigned H = ford(__float_as_uint(b)) + 1u;
            while (L < H) {                    // <= 31 iters, setup-only
                const unsigned M = L + ((H - L) >> 1);   // M <= ord(b): valid
                const float xm = __uint_as_float(funord(M));
                const float tL = xm - a;
                const float tR = xm - b;
                const float dL = tL * tL;      // same double-rounding as ref
                const float dR = tR * tR;
                const bool takeR = (dR == dL) ? tiewin : (dR < dL);
                if (takeR) H = M; else L = M + 1;
            }
            LUT[rr][i] = __uint_as_float(funord(L));
        }
    }
    __syncthreads();

    // ---- Phase 3: hot loop — rank(x) over thresholds, then gather ---------
#pragma unroll
    for (int rr = 0; rr < ROWS_PER_BLOCK; ++rr) {
        const char* base = (const char*)&LUT[rr][0];
        const float t4  = LUT[rr][4];
        const float t8  = LUT[rr][8];
        const float t12 = LUT[rr][12];
        f32x4* outr = (f32x4*)(out + (size_t)(row0 + rr) * N_COLS);

#pragma unroll
        for (int it = 0; it < 2; ++it) {
            const f32x4 v = (rr == 0) ? (it == 0 ? xv0 : xv1)
                                      : (it == 0 ? xv2 : xv3);
            f32x4 o;
#pragma unroll
            for (int e = 0; e < 4; ++e) {
                const float xe = v[e];
                // Branchless "find last k with T[k] <= x" over T[1..15];
                // posB = 4*k bytes. Levels 1-2 from registers, 3-4 from LDS.
                const bool b1 = (t8 <= xe);
                int posB = b1 ? 32 : 0;
                const float tq = b1 ? t12 : t4;
                posB += (tq <= xe) ? 16 : 0;
                posB += (*(const float*)(base + posB + 8) <= xe) ? 8 : 0;
                posB += (*(const float*)(base + posB + 4) <= xe) ? 4 : 0;
                o[e] = *(const float*)(base + posB + 64);   // sorted[rank]
            }
            outr[it * 256 + tid] = o;
        }
    }
}

extern "C" void kernel_launch(void* const* d_in, const int* in_sizes, int n_in,
                              void* d_out, int out_size, void* d_ws, size_t ws_size,
                              hipStream_t stream) {
    const float* x      = (const float*)d_in[0];
    const float* values = (const float*)d_in[1];
    float* out          = (float*)d_out;

    vq_rowcodebook_kernel<<<N_ROWS / ROWS_PER_BLOCK, 256, 0, stream>>>(x, values, out);
}